// Round 4
// baseline (4917.701 us; speedup 1.0000x reference)
//
#include <hip/hip_runtime.h>

// BasalGanglia fused kernel (MI355X / gfx950), dtype-self-detecting.
// R2/R3 evidence: identical ~0.73 decorrelated error from two different
// implementations => dtype plumbing, not math. A detector kernel classifies
// d_in[0] as f32-vs-bf16 on device; the audited all-f32 body is instantiated
// for both {bf16 in/out} and {f32 in/out}.

typedef __bf16 bf16_t;
typedef __bf16 bf16x4v __attribute__((ext_vector_type(4)));

#define BTOT 8192
#define BM   16
#define NTHR 512
#define NBLK 512
#define VSTRIDE 308   // vstn row stride (floats); %4==0 for float4, bank-spread

struct Params {
  const void *stimulus, *deltavf, *hx0, *cx0;
  const void *w_vf0, *b_vf0, *w_vf1, *b_vf1, *w_vf2, *b_vf2, *w_vf3, *b_vf3;
  const void *w_jd1, *b_jd1, *w_jd2, *b_jd2, *w_kd1, *b_kd1, *w_kd2, *b_kd2;
  const void *w_sg, *b_sg, *w_gs, *b_gs, *w_glat, *b_glat, *w_slat, *b_slat;
  const void *w_d1gpi, *b_d1gpi, *w_stngpi, *b_stngpi;
  const void *w_ih, *b_ih, *w_hh, *b_hh;
  void* out;
};

struct __align__(16) Smem {
  float vstnF[BM * VSTRIDE];
  float xgpeF[2][BM * 20];
  float scratchF[2048];
  float h0f[BM * 64];
  float h1f[BM * 128];
  float hxs[BM * 20], cxs[BM * 20], V_D2f[BM * 20];
  float DPs[BM * 2], vgpis[BM * 2], lamS[BM];
  float bsumS[320];
};

struct LdF32 {
  static __device__ __forceinline__ float4 ld4(const void* p, int i) {
    return *(const float4*)((const float*)p + i);           // i % 4 == 0 at all call sites
  }
  static __device__ __forceinline__ float ld1(const void* p, int i) {
    return ((const float*)p)[i];
  }
};
struct LdB16 {
  static __device__ __forceinline__ float4 ld4(const void* p, int i) {
    bf16x4v v = *(const bf16x4v*)((const bf16_t*)p + i);    // 8B-aligned (i%4==0)
    return make_float4((float)v[0], (float)v[1], (float)v[2], (float)v[3]);
  }
  static __device__ __forceinline__ float ld1(const void* p, int i) {
    return (float)((const bf16_t*)p)[i];
  }
};

__device__ __forceinline__ float sigm(float x) { return 1.f / (1.f + expf(-x)); }

// ---------------------------------------------------------------------------
// Detector: reading an f32 buffer as bf16 gives ~1/128 elements whose
// "exponent" field is 0x00 or 0xFF (mantissa-bit patterns); a true bf16
// N(0,1) buffer gives none. flag[0] = 1.0 => buffers are f32.
// ---------------------------------------------------------------------------
__global__ void bg_detect(const void* stim, float* flag) {
  __shared__ int cnt;
  if (threadIdx.x == 0) cnt = 0;
  __syncthreads();
  const unsigned short* u = (const unsigned short*)stim;
  int c = 0;
  for (int i = threadIdx.x; i < 8192; i += 256) {
    int e = (u[i] >> 7) & 0xFF;
    if (e == 0x00 || e == 0xFF) c++;
  }
  atomicAdd(&cnt, c);
  __syncthreads();
  if (threadIdx.x == 0) flag[0] = (cnt >= 4) ? 1.0f : 0.0f;
}

// ---------------------------------------------------------------------------
// The audited all-f32 body (identical math to R3), templated on input loader
// and output dtype.
// ---------------------------------------------------------------------------
template <class L, bool OF32>
__device__ void bg_body(const Params& P, Smem& S) {
  const int tid  = threadIdx.x;
  const int lane = tid & 63;
  const int wv   = tid >> 6;
  const int nL   = lane & 15;
  const int mg   = lane >> 4;
  const int row0 = blockIdx.x * BM;

  // ================= pre-loop =================
  if (tid < BM) S.lamS[tid] = sigm(L::ld1(P.deltavf, row0 + tid));
  for (int i = tid; i < BM * 20; i += NTHR) {
    S.hxs[i] = L::ld1(P.hx0, row0 * 20 + i);
    S.cxs[i] = L::ld1(P.cx0, row0 * 20 + i);
  }
  for (int i = tid; i < BM * 2; i += NTHR) S.vgpis[i] = 0.f;
  for (int i = tid; i < 2 * BM * 20; i += NTHR) ((float*)S.xgpeF)[i] = 0.f;
  for (int i = tid; i < BM * VSTRIDE; i += NTHR) S.vstnF[i] = 0.f;
  for (int i = tid; i < 320; i += NTHR)
    S.bsumS[i] = (i < 300) ? (L::ld1(P.b_slat, i) + L::ld1(P.b_gs, i)) : 0.f;

  { // h0 = relu(stim @ w_vf0^T + b): thread = (o, 2 rows)
    int o = tid & 63, mb = (tid >> 6) * 2;
    float bias = L::ld1(P.b_vf0, o), a0 = bias, a1 = bias;
    for (int kq = 0; kq < 75; ++kq) {
      float4 w  = L::ld4(P.w_vf0, o * 300 + kq * 4);
      float4 v0 = L::ld4(P.stimulus, (row0 + mb) * 300 + kq * 4);
      float4 v1 = L::ld4(P.stimulus, (row0 + mb + 1) * 300 + kq * 4);
      a0 = fmaf(v0.x, w.x, a0); a0 = fmaf(v0.y, w.y, a0); a0 = fmaf(v0.z, w.z, a0); a0 = fmaf(v0.w, w.w, a0);
      a1 = fmaf(v1.x, w.x, a1); a1 = fmaf(v1.y, w.y, a1); a1 = fmaf(v1.z, w.z, a1); a1 = fmaf(v1.w, w.w, a1);
    }
    S.h0f[(mb + 0) * 64 + o] = fmaxf(a0, 0.f);
    S.h0f[(mb + 1) * 64 + o] = fmaxf(a1, 0.f);
  }
  __syncthreads();
  { // h1
    int o = tid & 127, mb = (tid >> 7) * 4;
    float bias = L::ld1(P.b_vf1, o), a[4];
#pragma unroll
    for (int u = 0; u < 4; ++u) a[u] = bias;
    for (int k = 0; k < 64; ++k) {
      float w = L::ld1(P.w_vf1, o * 64 + k);
#pragma unroll
      for (int u = 0; u < 4; ++u) a[u] = fmaf(S.h0f[(mb + u) * 64 + k], w, a[u]);
    }
#pragma unroll
    for (int u = 0; u < 4; ++u) S.h1f[(mb + u) * 128 + o] = fmaxf(a[u], 0.f);
  }
  __syncthreads();
  { // h2 -> overwrite h0f
    int o = tid & 63, mb = (tid >> 6) * 2;
    float bias = L::ld1(P.b_vf2, o), a0 = bias, a1 = bias;
    for (int k = 0; k < 128; ++k) {
      float w = L::ld1(P.w_vf2, o * 128 + k);
      a0 = fmaf(S.h1f[(mb + 0) * 128 + k], w, a0);
      a1 = fmaf(S.h1f[(mb + 1) * 128 + k], w, a1);
    }
    S.h0f[(mb + 0) * 64 + o] = fmaxf(a0, 0.f);
    S.h0f[(mb + 1) * 64 + o] = fmaxf(a1, 0.f);
  }
  __syncthreads();
  { // drives -> scratchF[0:1280); vt output
    int oid = tid & 127, mb = (tid >> 7) * 4;
    if (oid < 80) {
      int which = oid / 20, o = oid - which * 20;
      const void *wp, *bp;
      if (which == 0)      { wp = P.w_jd1; bp = P.b_jd1; }
      else if (which == 1) { wp = P.w_jd2; bp = P.b_jd2; }
      else if (which == 2) { wp = P.w_kd1; bp = P.b_kd1; }
      else                 { wp = P.w_kd2; bp = P.b_kd2; }
      float bias = L::ld1(bp, o), a[4];
#pragma unroll
      for (int u = 0; u < 4; ++u) a[u] = bias;
      for (int kq = 0; kq < 75; ++kq) {
        float4 w = L::ld4(wp, o * 300 + kq * 4);
#pragma unroll
        for (int u = 0; u < 4; ++u) {
          float4 v = L::ld4(P.stimulus, (row0 + mb + u) * 300 + kq * 4);
          a[u] = fmaf(v.x, w.x, a[u]); a[u] = fmaf(v.y, w.y, a[u]);
          a[u] = fmaf(v.z, w.z, a[u]); a[u] = fmaf(v.w, w.w, a[u]);
        }
      }
#pragma unroll
      for (int u = 0; u < 4; ++u) S.scratchF[which * 320 + (mb + u) * 20 + o] = a[u];
    }
    if (tid < BM) { // vt = tanh(h2 @ w_vf3^T + b)
      float a = L::ld1(P.b_vf3, 0);
      for (int k = 0; k < 64; ++k) a = fmaf(S.h0f[tid * 64 + k], L::ld1(P.w_vf3, k), a);
      float vt = tanhf(a);
      if (OF32) ((float*)P.out)[(size_t)BTOT * 20 + row0 + tid] = vt;
      else      ((bf16_t*)P.out)[(size_t)BTOT * 20 + row0 + tid] = (bf16_t)vt;
    }
  }
  __syncthreads();
  // FF loop -> V_D1 (scratchF[1280:1600)), V_D2f
  if (tid < BM * 20) {
    int i = tid, m = i / 20;
    float j1 = S.scratchF[i], j2 = S.scratchF[320 + i];
    float k1 = S.scratchF[640 + i], k2 = S.scratchF[960 + i];
    float Lm = S.lamS[m], v1 = 0.f, v2 = 0.f;
    for (int s = 0; s < 20; ++s) {
      v1 = sigm(Lm * (j1 * (1.f - v1) + (1.f - k1) * v1));
      v2 = sigm(Lm * (j2 * (1.f - v2) + (1.f - k2) * v2));
    }
    S.scratchF[1280 + i] = v1;
    S.V_D2f[i] = v2;
  }
  __syncthreads();
  if (tid < BM * 2) { // V_GPi_DP
    int m = tid >> 1, p2 = tid & 1;
    float a = L::ld1(P.b_d1gpi, p2);
    for (int o = 0; o < 20; ++o) a = fmaf(S.scratchF[1280 + m * 20 + o], L::ld1(P.w_d1gpi, p2 * 20 + o), a);
    S.DPs[tid] = a;
  }
  __syncthreads();

  float xs[3][4];
#pragma unroll
  for (int no = 0; no < 3; ++no)
#pragma unroll
    for (int mo = 0; mo < 4; ++mo) xs[no][mo] = 0.f;

  // ================= STN recurrence =================
  for (int it = 0; it < 50; ++it) {
    const int po = it & 1, pn = po ^ 1;

    // Phase A: xgpe_new = sg@vstn + glat@xgpe_old + b_sg + b_glat - V_D2
    if (tid < BM * 20) {
      int m = tid / 20, g = tid - m * 20;
      float acc = L::ld1(P.b_sg, g) + L::ld1(P.b_glat, g) - S.V_D2f[m * 20 + g];
      const float4* vr = (const float4*)&S.vstnF[m * VSTRIDE];
#pragma unroll 5
      for (int kq = 0; kq < 75; ++kq) {
        float4 w = L::ld4(P.w_sg, g * 300 + kq * 4), v = vr[kq];
        acc = fmaf(v.x, w.x, acc); acc = fmaf(v.y, w.y, acc);
        acc = fmaf(v.z, w.z, acc); acc = fmaf(v.w, w.w, acc);
      }
      const float4* xr = (const float4*)&S.xgpeF[po][m * 20];
#pragma unroll
      for (int kq = 0; kq < 5; ++kq) {
        float4 w = L::ld4(P.w_glat, g * 20 + kq * 4), v = xr[kq];
        acc = fmaf(v.x, w.x, acc); acc = fmaf(v.y, w.y, acc);
        acc = fmaf(v.z, w.z, acc); acc = fmaf(v.w, w.w, acc);
      }
      S.xgpeF[pn][m * 20 + g] = acc;
    }
    __syncthreads();

    // Phase B dots: slat@vstn + gs@xgpe_new
    float accv[3][4];
#pragma unroll
    for (int no = 0; no < 3; ++no) {
      if (no == 2 && wv >= 3) continue;
      const int n  = no * 128 + wv * 16 + nL;
      const int nn = (n < 300) ? n : 0;
      float a0 = 0.f, a1 = 0.f, a2 = 0.f, a3 = 0.f;
#pragma unroll 5
      for (int kq = 0; kq < 75; ++kq) {
        float4 w  = L::ld4(P.w_slat, nn * 300 + kq * 4);
        float4 v0 = *(const float4*)&S.vstnF[(mg + 0) * VSTRIDE + kq * 4];
        float4 v1 = *(const float4*)&S.vstnF[(mg + 4) * VSTRIDE + kq * 4];
        float4 v2 = *(const float4*)&S.vstnF[(mg + 8) * VSTRIDE + kq * 4];
        float4 v3 = *(const float4*)&S.vstnF[(mg + 12) * VSTRIDE + kq * 4];
        a0 = fmaf(v0.x, w.x, a0); a0 = fmaf(v0.y, w.y, a0); a0 = fmaf(v0.z, w.z, a0); a0 = fmaf(v0.w, w.w, a0);
        a1 = fmaf(v1.x, w.x, a1); a1 = fmaf(v1.y, w.y, a1); a1 = fmaf(v1.z, w.z, a1); a1 = fmaf(v1.w, w.w, a1);
        a2 = fmaf(v2.x, w.x, a2); a2 = fmaf(v2.y, w.y, a2); a2 = fmaf(v2.z, w.z, a2); a2 = fmaf(v2.w, w.w, a2);
        a3 = fmaf(v3.x, w.x, a3); a3 = fmaf(v3.y, w.y, a3); a3 = fmaf(v3.z, w.z, a3); a3 = fmaf(v3.w, w.w, a3);
      }
#pragma unroll
      for (int kq = 0; kq < 5; ++kq) {
        float4 w  = L::ld4(P.w_gs, nn * 20 + kq * 4);
        float4 v0 = *(const float4*)&S.xgpeF[pn][(mg + 0) * 20 + kq * 4];
        float4 v1 = *(const float4*)&S.xgpeF[pn][(mg + 4) * 20 + kq * 4];
        float4 v2 = *(const float4*)&S.xgpeF[pn][(mg + 8) * 20 + kq * 4];
        float4 v3 = *(const float4*)&S.xgpeF[pn][(mg + 12) * 20 + kq * 4];
        a0 = fmaf(v0.x, w.x, a0); a0 = fmaf(v0.y, w.y, a0); a0 = fmaf(v0.z, w.z, a0); a0 = fmaf(v0.w, w.w, a0);
        a1 = fmaf(v1.x, w.x, a1); a1 = fmaf(v1.y, w.y, a1); a1 = fmaf(v1.z, w.z, a1); a1 = fmaf(v1.w, w.w, a1);
        a2 = fmaf(v2.x, w.x, a2); a2 = fmaf(v2.y, w.y, a2); a2 = fmaf(v2.z, w.z, a2); a2 = fmaf(v2.w, w.w, a2);
        a3 = fmaf(v3.x, w.x, a3); a3 = fmaf(v3.y, w.y, a3); a3 = fmaf(v3.z, w.z, a3); a3 = fmaf(v3.w, w.w, a3);
      }
      accv[no][0] = a0; accv[no][1] = a1; accv[no][2] = a2; accv[no][3] = a3;
    }
    __syncthreads();

    // Phase B epilogue
#pragma unroll
    for (int no = 0; no < 3; ++no) {
      if (no == 2 && wv >= 3) continue;
      const int n = no * 128 + wv * 16 + nL;
      const float bn = S.bsumS[n];
#pragma unroll
      for (int mo = 0; mo < 4; ++mo) {
        const int m = mg + 4 * mo;
        float xo = xs[no][mo];
        float xn = xo + (1.0f / 3.0f) * (accv[no][mo] + bn - xo);
        xs[no][mo] = xn;
        if (n < 300) S.vstnF[m * VSTRIDE + n] = tanhf(S.lamS[m] * xn);
      }
    }
    __syncthreads();

    // Phase C: stngpi partials -> vgpi -> LSTM
    if (tid < 256) {
      int m = tid >> 4, p2 = (tid >> 3) & 1, kc = tid & 7;
      int k0 = kc * 38, k1 = k0 + 38; if (k1 > 300) k1 = 300;
      float s = 0.f;
      for (int k = k0; k < k1; ++k) s = fmaf(S.vstnF[m * VSTRIDE + k], L::ld1(P.w_stngpi, p2 * 300 + k), s);
      S.scratchF[1600 + tid] = s;
    }
    __syncthreads();
    if (tid < BM * 2) {
      int m = tid >> 1, p2 = tid & 1;
      float s = L::ld1(P.b_stngpi, p2);
#pragma unroll
      for (int kc = 0; kc < 8; ++kc) s += S.scratchF[1600 + m * 16 + p2 * 8 + kc];
      float ip = S.lamS[m] * s;
      float v = S.vgpis[tid];
      S.vgpis[tid] = v + 0.1f * (-v - S.DPs[tid] + 2.f * ip);
    }
    __syncthreads();
    for (int i = tid; i < BM * 80; i += NTHR) { // gates
      int m = i / 80, gg = i - m * 80;
      float a = L::ld1(P.b_ih, gg) + L::ld1(P.b_hh, gg);
      a = fmaf(L::ld1(P.w_ih, gg * 2 + 0), -S.vgpis[m * 2 + 0], a);
      a = fmaf(L::ld1(P.w_ih, gg * 2 + 1), -S.vgpis[m * 2 + 1], a);
      const float* hr = S.hxs + m * 20;
#pragma unroll
      for (int k = 0; k < 20; ++k) a = fmaf(L::ld1(P.w_hh, gg * 20 + k), hr[k], a);
      S.scratchF[i] = a;
    }
    __syncthreads();
    if (tid < BM * 20) { // LSTM pointwise (i,f,g,o)
      int i = tid, m = i / 20, jj = i - m * 20;
      float si = sigm(S.scratchF[m * 80 + jj]);
      float sf = sigm(S.scratchF[m * 80 + 20 + jj]);
      float gG = tanhf(S.scratchF[m * 80 + 40 + jj]);
      float so = sigm(S.scratchF[m * 80 + 60 + jj]);
      float cn = sf * S.cxs[i] + si * gG;
      S.cxs[i] = cn;
      S.hxs[i] = so * tanhf(cn);
    }
    __syncthreads();
  }

  for (int i = tid; i < BM * 20; i += NTHR) {
    float v = S.hxs[i];
    if (OF32) ((float*)P.out)[(size_t)row0 * 20 + i] = v;
    else      ((bf16_t*)P.out)[(size_t)row0 * 20 + i] = (bf16_t)v;
  }
}

__global__ __launch_bounds__(NTHR) void bg_main(Params P, const float* flag, int fmode) {
  __shared__ Smem S;
  bool f32in = (fmode == 1) ? true : (*flag > 0.5f);
  if (f32in) bg_body<LdF32, true >(P, S);
  else       bg_body<LdB16, false>(P, S);
}

extern "C" void kernel_launch(void* const* d_in, const int* in_sizes, int n_in,
                              void* d_out, int out_size, void* d_ws, size_t ws_size,
                              hipStream_t stream) {
  (void)in_sizes; (void)n_in; (void)out_size;
  Params P;
  P.stimulus = d_in[0];  P.deltavf = d_in[1];  P.hx0 = d_in[2];  P.cx0 = d_in[3];
  P.w_vf0 = d_in[4];  P.b_vf0 = d_in[5];  P.w_vf1 = d_in[6];  P.b_vf1 = d_in[7];
  P.w_vf2 = d_in[8];  P.b_vf2 = d_in[9];  P.w_vf3 = d_in[10]; P.b_vf3 = d_in[11];
  P.w_jd1 = d_in[12]; P.b_jd1 = d_in[13]; P.w_jd2 = d_in[14]; P.b_jd2 = d_in[15];
  P.w_kd1 = d_in[16]; P.b_kd1 = d_in[17]; P.w_kd2 = d_in[18]; P.b_kd2 = d_in[19];
  P.w_sg  = d_in[20]; P.b_sg  = d_in[21]; P.w_gs  = d_in[22]; P.b_gs  = d_in[23];
  P.w_glat= d_in[24]; P.b_glat= d_in[25]; P.w_slat= d_in[26]; P.b_slat= d_in[27];
  P.w_d1gpi  = d_in[28]; P.b_d1gpi  = d_in[29];
  P.w_stngpi = d_in[30]; P.b_stngpi = d_in[31];
  P.w_ih = d_in[32]; P.b_ih = d_in[33]; P.w_hh = d_in[34]; P.b_hh = d_in[35];
  P.out = d_out;

  int fmode = 0;
  const float* flag = (const float*)d_ws;
  if (ws_size < 4) { fmode = 1; flag = nullptr; }           // fallback: assume f32
  else bg_detect<<<1, 256, 0, stream>>>(d_in[0], (float*)d_ws);
  bg_main<<<NBLK, NTHR, 0, stream>>>(P, flag, fmode);
}

// Round 5
// 599.702 us; speedup vs baseline: 8.2002x; 8.2002x over previous
//
#include <hip/hip_runtime.h>

// BasalGanglia fused kernel (MI355X / gfx950).
// Established R4: inputs f32, outputs f32 (WRITE_SIZE evidence), f32 recurrence
// absmax 9.8e-4 vs 9.53e-3 threshold. This round: f16 MFMA for all recurrence
// matmuls (slat/sg/gs/glat/stngpi/LSTM-gates), B-fragments register-resident,
// state planes (vstn/xgpe/hx) f16 in LDS, integrator state (xstn/cx/vgpi) f32.

typedef _Float16 f16_t;
typedef _Float16 f16x8 __attribute__((ext_vector_type(8)));
typedef float floatx4 __attribute__((ext_vector_type(4)));

#define BTOT 8192
#define BM   32
#define NTHR 512
#define NBLK 256
#define VSTR 328   // f16 elems; row byte-stride 656 = 164 dwords -> m,m+8 2-way (free)
#define XSTR 40    // f16 elems; 80 B = 20 dwords -> 2-way (free)

struct Params {
  const float *stimulus, *deltavf, *hx0, *cx0;
  const float *w_vf0, *b_vf0, *w_vf1, *b_vf1, *w_vf2, *b_vf2, *w_vf3, *b_vf3;
  const float *w_jd1, *b_jd1, *w_jd2, *b_jd2, *w_kd1, *b_kd1, *w_kd2, *b_kd2;
  const float *w_sg, *b_sg, *w_gs, *b_gs, *w_glat, *b_glat, *w_slat, *b_slat;
  const float *w_d1gpi, *b_d1gpi, *w_stngpi, *b_stngpi;
  const float *w_ih, *b_ih, *w_hh, *b_hh;
  float* out;
};

struct __align__(16) Smem {
  f16_t vstn[BM * VSTR];                                   // 20992 B
  f16_t xgpe[BM * XSTR];                                   // 2560
  f16_t hxf[BM * XSTR];                                    // 2560: [0:20)=hx, [20:22)=-vgpi, rest 0
  union { float h1f[BM * 128]; float scratchF[3200]; } u;  // 16384
  float h0f[BM * 64];                                      // 8192
  float hxs[BM * 20], cxs[BM * 20], V_D2f[BM * 20];        // 7680
  float DPs[BM * 2], vgpis[BM * 2], lamS[BM];              // 640
};

__device__ __forceinline__ float sigm(float x) { return 1.f / (1.f + expf(-x)); }

// Load 8 consecutive f32 weights row[k0..k0+7] -> f16x8, zeroing k >= kmax.
// (kmax - k0) is always a multiple of 4 at call sites, so float4-granular.
__device__ __forceinline__ f16x8 ldfrag(const float* row, int k0, int kmax, bool valid) {
  float4 z = make_float4(0.f, 0.f, 0.f, 0.f);
  int nv = valid ? (kmax - k0) : 0;
  float4 f0 = (nv >= 4) ? *(const float4*)(row + k0) : z;
  float4 f1 = (nv >= 8) ? *(const float4*)(row + k0 + 4) : z;
  f16x8 r;
  r[0] = (f16_t)f0.x; r[1] = (f16_t)f0.y; r[2] = (f16_t)f0.z; r[3] = (f16_t)f0.w;
  r[4] = (f16_t)f1.x; r[5] = (f16_t)f1.y; r[6] = (f16_t)f1.z; r[7] = (f16_t)f1.w;
  return r;
}

__global__ __launch_bounds__(NTHR, 2) void bg_main(Params P) {
  __shared__ Smem S;
  const int tid  = threadIdx.x;
  const int lane = tid & 63;
  const int wv   = tid >> 6;      // 0..7
  const int q    = lane >> 4;     // quad 0..3
  const int cl   = lane & 15;
  const int row0 = blockIdx.x * BM;

  // ================= init =================
  if (tid < BM) S.lamS[tid] = sigm(P.deltavf[row0 + tid]);
  for (int i = tid; i < BM * 20; i += NTHR) {
    float h = P.hx0[row0 * 20 + i];
    S.hxs[i] = h;
    S.cxs[i] = P.cx0[row0 * 20 + i];
    int m = i / 20, j = i - m * 20;
    S.hxf[m * XSTR + j] = (f16_t)h;
  }
  for (int i = tid; i < BM * 2; i += NTHR) S.vgpis[i] = 0.f;
  for (int i = tid; i < BM * XSTR; i += NTHR) S.xgpe[i] = (f16_t)0.f;
  for (int i = tid; i < BM * XSTR; i += NTHR) {
    int m = i / XSTR, j = i - m * XSTR;
    if (j >= 20) S.hxf[i] = (f16_t)0.f;   // -vgpi slots (vgpi0=0) + pad
  }
  for (int i = tid; i < BM * VSTR; i += NTHR) S.vstn[i] = (f16_t)0.f;

  { // h0 = relu(stim @ w_vf0^T + b): thread = (o, 4 rows)
    int o = tid & 63, mb = (tid >> 6) * 4;
    const float4* wr = (const float4*)(P.w_vf0 + o * 300);
    float bias = P.b_vf0[o], a[4];
#pragma unroll
    for (int u = 0; u < 4; ++u) a[u] = bias;
    for (int kq = 0; kq < 75; ++kq) {
      float4 w = wr[kq];
#pragma unroll
      for (int u = 0; u < 4; ++u) {
        float4 v = *(const float4*)(P.stimulus + (size_t)(row0 + mb + u) * 300 + kq * 4);
        a[u] = fmaf(v.x, w.x, a[u]); a[u] = fmaf(v.y, w.y, a[u]);
        a[u] = fmaf(v.z, w.z, a[u]); a[u] = fmaf(v.w, w.w, a[u]);
      }
    }
#pragma unroll
    for (int u = 0; u < 4; ++u) S.h0f[(mb + u) * 64 + o] = fmaxf(a[u], 0.f);
  }
  __syncthreads();
  { // h1
    int o = tid & 127, mb = (tid >> 7) * 8;
    const float* wr = P.w_vf1 + o * 64;
    float bias = P.b_vf1[o], a[8];
#pragma unroll
    for (int u = 0; u < 8; ++u) a[u] = bias;
    for (int k = 0; k < 64; ++k) {
      float w = wr[k];
#pragma unroll
      for (int u = 0; u < 8; ++u) a[u] = fmaf(S.h0f[(mb + u) * 64 + k], w, a[u]);
    }
#pragma unroll
    for (int u = 0; u < 8; ++u) S.u.h1f[(mb + u) * 128 + o] = fmaxf(a[u], 0.f);
  }
  __syncthreads();
  { // h2 -> overwrite h0f
    int o = tid & 63, mb = (tid >> 6) * 4;
    const float* wr = P.w_vf2 + o * 128;
    float bias = P.b_vf2[o], a[4];
#pragma unroll
    for (int u = 0; u < 4; ++u) a[u] = bias;
    for (int k = 0; k < 128; ++k) {
      float w = wr[k];
#pragma unroll
      for (int u = 0; u < 4; ++u) a[u] = fmaf(S.u.h1f[(mb + u) * 128 + k], w, a[u]);
    }
#pragma unroll
    for (int u = 0; u < 4; ++u) S.h0f[(mb + u) * 64 + o] = fmaxf(a[u], 0.f);
  }
  __syncthreads();
  { // drives -> scratchF[0:2560) (overwrites h1f region; h1f dead); vt output
    int oid = tid & 127, mb = (tid >> 7) * 8;
    if (oid < 80) {
      int which = oid / 20, o = oid - which * 20;
      const float *wp, *bp;
      if (which == 0)      { wp = P.w_jd1; bp = P.b_jd1; }
      else if (which == 1) { wp = P.w_jd2; bp = P.b_jd2; }
      else if (which == 2) { wp = P.w_kd1; bp = P.b_kd1; }
      else                 { wp = P.w_kd2; bp = P.b_kd2; }
      float bias = bp[o], a[8];
#pragma unroll
      for (int u = 0; u < 8; ++u) a[u] = bias;
      for (int kq = 0; kq < 75; ++kq) {
        float4 w = *(const float4*)(wp + o * 300 + kq * 4);
#pragma unroll
        for (int u = 0; u < 8; ++u) {
          float4 v = *(const float4*)(P.stimulus + (size_t)(row0 + mb + u) * 300 + kq * 4);
          a[u] = fmaf(v.x, w.x, a[u]); a[u] = fmaf(v.y, w.y, a[u]);
          a[u] = fmaf(v.z, w.z, a[u]); a[u] = fmaf(v.w, w.w, a[u]);
        }
      }
#pragma unroll
      for (int u = 0; u < 8; ++u) S.u.scratchF[which * 640 + (mb + u) * 20 + o] = a[u];
    }
    if (tid < BM) { // vt = tanh(h2 @ w_vf3^T + b)
      float a = P.b_vf3[0];
      for (int k = 0; k < 64; ++k) a = fmaf(S.h0f[tid * 64 + k], P.w_vf3[k], a);
      P.out[(size_t)BTOT * 20 + row0 + tid] = tanhf(a);
    }
  }
  __syncthreads();
  // FF -> V_D1 (scratchF[2560:3200)), V_D2f
  for (int i = tid; i < BM * 20; i += NTHR) {
    int m = i / 20;
    float j1 = S.u.scratchF[i],        j2 = S.u.scratchF[640 + i];
    float k1 = S.u.scratchF[1280 + i], k2 = S.u.scratchF[1920 + i];
    float L = S.lamS[m], v1 = 0.f, v2 = 0.f;
    for (int s = 0; s < 20; ++s) {
      v1 = sigm(L * (j1 * (1.f - v1) + (1.f - k1) * v1));
      v2 = sigm(L * (j2 * (1.f - v2) + (1.f - k2) * v2));
    }
    S.u.scratchF[2560 + i] = v1;
    S.V_D2f[i] = v2;
  }
  __syncthreads();
  if (tid < BM * 2) { // V_GPi_DP
    int m = tid >> 1, p2 = tid & 1;
    float a = P.b_d1gpi[p2];
    for (int o = 0; o < 20; ++o) a = fmaf(S.u.scratchF[2560 + m * 20 + o], P.w_d1gpi[p2 * 20 + o], a);
    S.DPs[tid] = a;
  }
  __syncthreads();

  // ================= register-resident f16 B-fragments =================
  // B-frag (16x16x32): lane holds B[k][n], n=lane&15, k=q*8+j.
  f16x8 Bs[3][10], Bgs[3], Bglat, Bsp[10], Bhh;
  {
    f16x8 z;
#pragma unroll
    for (int e = 0; e < 8; ++e) z[e] = (f16_t)0.f;
    Bglat = z; Bhh = z;
#pragma unroll
    for (int c = 0; c < 10; ++c) Bsp[c] = z;
#pragma unroll
    for (int j = 0; j < 3; ++j) {
      Bgs[j] = z;
      int t = wv + 8 * j;
      if (t < 19) {                 // slat tiles
        int n = t * 16 + cl, nn = (n < 300) ? n : 0;
#pragma unroll
        for (int c = 0; c < 10; ++c)
          Bs[j][c] = ldfrag(P.w_slat + (size_t)nn * 300, c * 32 + q * 8, 300, n < 300);
        Bgs[j] = ldfrag(P.w_gs + (size_t)nn * 20, q * 8, 20, n < 300);
      } else if (t < 21) {          // sg tiles (19, 20)
        int g = (t - 19) * 16 + cl, gg = (g < 20) ? g : 0;
#pragma unroll
        for (int c = 0; c < 10; ++c)
          Bs[j][c] = ldfrag(P.w_sg + (size_t)gg * 300, c * 32 + q * 8, 300, g < 20);
        Bglat = ldfrag(P.w_glat + (size_t)gg * 20, q * 8, 20, g < 20);
      } else {
#pragma unroll
        for (int c = 0; c < 10; ++c) Bs[j][c] = z;
      }
    }
    if (wv == 5) {                  // stngpi: rows p=0,1
      int pp = (cl < 2) ? cl : 0;
#pragma unroll
      for (int c = 0; c < 10; ++c)
        Bsp[c] = ldfrag(P.w_stngpi + (size_t)pp * 300, c * 32 + q * 8, 300, cl < 2);
    }
    if (wv < 5) {                   // LSTM gates: K = [hx(20) | -vgpi(2)]
      int g = wv * 16 + cl;
#pragma unroll
      for (int j = 0; j < 8; ++j) {
        int k = q * 8 + j;
        float v = 0.f;
        if (k < 20)      v = P.w_hh[g * 20 + k];
        else if (k < 22) v = P.w_ih[g * 2 + (k - 20)];
        Bhh[j] = (f16_t)v;
      }
    }
  }
  // per-lane biases / lam
  float bsum[3];
#pragma unroll
  for (int j = 0; j < 3; ++j) {
    int t = wv + 8 * j;
    bsum[j] = 0.f;
    if (t < 19) { int n = t * 16 + cl; if (n < 300) bsum[j] = P.b_slat[n] + P.b_gs[n]; }
    else if (t < 21) { int g = (t - 19) * 16 + cl; if (g < 20) bsum[j] = P.b_sg[g] + P.b_glat[g]; }
  }
  float bstn  = (wv == 5 && cl < 2) ? P.b_stngpi[cl] : 0.f;
  float bsumg = (wv < 5) ? (P.b_ih[wv * 16 + cl] + P.b_hh[wv * 16 + cl]) : 0.f;
  float lamr[2][4];
#pragma unroll
  for (int mt = 0; mt < 2; ++mt)
#pragma unroll
    for (int r = 0; r < 4; ++r) lamr[mt][r] = S.lamS[mt * 16 + q * 4 + r];

  float xs[3][2][4];
#pragma unroll
  for (int j = 0; j < 3; ++j)
#pragma unroll
    for (int mt = 0; mt < 2; ++mt)
#pragma unroll
      for (int r = 0; r < 4; ++r) xs[j][mt][r] = 0.f;

  const bool sgw = (wv == 3 || wv == 4);
  const floatx4 zf = {0.f, 0.f, 0.f, 0.f};

  // ================= STN recurrence, 50 iterations =================
  for (int it = 0; it < 50; ++it) {
    floatx4 acc[3][2];
#pragma unroll
    for (int j = 0; j < 3; ++j) { acc[j][0] = zf; acc[j][1] = zf; }

    // ---- Phase A: [slat|sg] @ vstn (+ glat @ xgpe_old for sg tiles) ----
#pragma unroll
    for (int c = 0; c < 10; ++c) {
      f16x8 a0 = *(const f16x8*)&S.vstn[cl * VSTR + c * 32 + q * 8];
      f16x8 a1 = *(const f16x8*)&S.vstn[(16 + cl) * VSTR + c * 32 + q * 8];
#pragma unroll
      for (int j = 0; j < 3; ++j) {
        if (wv + 8 * j < 21) {
          acc[j][0] = __builtin_amdgcn_mfma_f32_16x16x32_f16(a0, Bs[j][c], acc[j][0], 0, 0, 0);
          acc[j][1] = __builtin_amdgcn_mfma_f32_16x16x32_f16(a1, Bs[j][c], acc[j][1], 0, 0, 0);
        }
      }
    }
    if (sgw) {
      f16x8 g0 = *(const f16x8*)&S.xgpe[cl * XSTR + q * 8];
      f16x8 g1 = *(const f16x8*)&S.xgpe[(16 + cl) * XSTR + q * 8];
      acc[2][0] = __builtin_amdgcn_mfma_f32_16x16x32_f16(g0, Bglat, acc[2][0], 0, 0, 0);
      acc[2][1] = __builtin_amdgcn_mfma_f32_16x16x32_f16(g1, Bglat, acc[2][1], 0, 0, 0);
      int g = (wv - 3) * 16 + cl;   // only sgwaves touch xgpe: within-wave RAW -> no barrier
      if (g < 20) {
#pragma unroll
        for (int mt = 0; mt < 2; ++mt)
#pragma unroll
          for (int r = 0; r < 4; ++r) {
            int m = mt * 16 + q * 4 + r;
            S.xgpe[m * XSTR + g] = (f16_t)(acc[2][mt][r] + bsum[2] - S.V_D2f[m * 20 + g]);
          }
      }
    }
    __syncthreads(); // b1: xgpe_new published; all vstn reads done

    // ---- Phase B: acc += gs @ xgpe_new; xstn update; vstn_new ----
    {
      f16x8 g0 = *(const f16x8*)&S.xgpe[cl * XSTR + q * 8];
      f16x8 g1 = *(const f16x8*)&S.xgpe[(16 + cl) * XSTR + q * 8];
#pragma unroll
      for (int j = 0; j < 3; ++j) {
        if (wv + 8 * j < 19) {
          acc[j][0] = __builtin_amdgcn_mfma_f32_16x16x32_f16(g0, Bgs[j], acc[j][0], 0, 0, 0);
          acc[j][1] = __builtin_amdgcn_mfma_f32_16x16x32_f16(g1, Bgs[j], acc[j][1], 0, 0, 0);
        }
      }
#pragma unroll
      for (int j = 0; j < 3; ++j) {
        int t = wv + 8 * j;
        if (t < 19) {
          int n = t * 16 + cl;
          if (n < 300) {
#pragma unroll
            for (int mt = 0; mt < 2; ++mt)
#pragma unroll
              for (int r = 0; r < 4; ++r) {
                int m = mt * 16 + q * 4 + r;
                float xo = xs[j][mt][r];
                float xn = xo + (1.0f / 3.0f) * (acc[j][mt][r] + bsum[j] - xo);
                xs[j][mt][r] = xn;
                S.vstn[m * VSTR + n] = (f16_t)tanhf(lamr[mt][r] * xn);
              }
          }
        }
      }
    }
    __syncthreads(); // b2: vstn_new published

    // ---- Phase C (wave 5): stngpi MFMA -> vgpi update -> hxf[-vgpi] ----
    if (wv == 5) {
      floatx4 ip0 = zf, ip1 = zf;
#pragma unroll
      for (int c = 0; c < 10; ++c) {
        f16x8 a0 = *(const f16x8*)&S.vstn[cl * VSTR + c * 32 + q * 8];
        f16x8 a1 = *(const f16x8*)&S.vstn[(16 + cl) * VSTR + c * 32 + q * 8];
        ip0 = __builtin_amdgcn_mfma_f32_16x16x32_f16(a0, Bsp[c], ip0, 0, 0, 0);
        ip1 = __builtin_amdgcn_mfma_f32_16x16x32_f16(a1, Bsp[c], ip1, 0, 0, 0);
      }
      if (cl < 2) {
#pragma unroll
        for (int mt = 0; mt < 2; ++mt)
#pragma unroll
          for (int r = 0; r < 4; ++r) {
            int m = mt * 16 + q * 4 + r;
            float raw = (mt == 0 ? ip0[r] : ip1[r]) + bstn;
            float ipv = S.lamS[m] * raw;
            float v = S.vgpis[m * 2 + cl];
            v = v + 0.1f * (-v - S.DPs[m * 2 + cl] + 2.f * ipv);
            S.vgpis[m * 2 + cl] = v;
            S.hxf[m * XSTR + 20 + cl] = (f16_t)(-v);
          }
      }
    }
    __syncthreads(); // b3: -vgpi published

    // ---- Phase D (waves 0-4): gates = [hx|-vgpi] @ [w_hh|w_ih]^T ----
    if (wv < 5) {
      f16x8 h0 = *(const f16x8*)&S.hxf[cl * XSTR + q * 8];
      f16x8 h1 = *(const f16x8*)&S.hxf[(16 + cl) * XSTR + q * 8];
      floatx4 g0 = __builtin_amdgcn_mfma_f32_16x16x32_f16(h0, Bhh, zf, 0, 0, 0);
      floatx4 g1 = __builtin_amdgcn_mfma_f32_16x16x32_f16(h1, Bhh, zf, 0, 0, 0);
      int g = wv * 16 + cl;
#pragma unroll
      for (int mt = 0; mt < 2; ++mt)
#pragma unroll
        for (int r = 0; r < 4; ++r) {
          int m = mt * 16 + q * 4 + r;
          S.u.scratchF[m * 80 + g] = (mt == 0 ? g0[r] : g1[r]) + bsumg;
        }
    }
    __syncthreads(); // b4: gates published

    // ---- LSTM pointwise (i,f,g,o) ----
    for (int i = tid; i < BM * 20; i += NTHR) {
      int m = i / 20, j = i - m * 20;
      float si = sigm(S.u.scratchF[m * 80 + j]);
      float sf = sigm(S.u.scratchF[m * 80 + 20 + j]);
      float gG = tanhf(S.u.scratchF[m * 80 + 40 + j]);
      float so = sigm(S.u.scratchF[m * 80 + 60 + j]);
      float cn = sf * S.cxs[i] + si * gG;
      S.cxs[i] = cn;
      float hn = so * tanhf(cn);
      S.hxs[i] = hn;
      S.hxf[m * XSTR + j] = (f16_t)hn;
    }
    __syncthreads(); // b5
  }

  for (int i = tid; i < BM * 20; i += NTHR)
    P.out[(size_t)row0 * 20 + i] = S.hxs[i];
}

extern "C" void kernel_launch(void* const* d_in, const int* in_sizes, int n_in,
                              void* d_out, int out_size, void* d_ws, size_t ws_size,
                              hipStream_t stream) {
  (void)in_sizes; (void)n_in; (void)out_size; (void)d_ws; (void)ws_size;
  Params P;
  P.stimulus = (const float*)d_in[0];
  P.deltavf  = (const float*)d_in[1];
  P.hx0 = (const float*)d_in[2];
  P.cx0 = (const float*)d_in[3];
  P.w_vf0 = (const float*)d_in[4];  P.b_vf0 = (const float*)d_in[5];
  P.w_vf1 = (const float*)d_in[6];  P.b_vf1 = (const float*)d_in[7];
  P.w_vf2 = (const float*)d_in[8];  P.b_vf2 = (const float*)d_in[9];
  P.w_vf3 = (const float*)d_in[10]; P.b_vf3 = (const float*)d_in[11];
  P.w_jd1 = (const float*)d_in[12]; P.b_jd1 = (const float*)d_in[13];
  P.w_jd2 = (const float*)d_in[14]; P.b_jd2 = (const float*)d_in[15];
  P.w_kd1 = (const float*)d_in[16]; P.b_kd1 = (const float*)d_in[17];
  P.w_kd2 = (const float*)d_in[18]; P.b_kd2 = (const float*)d_in[19];
  P.w_sg  = (const float*)d_in[20]; P.b_sg  = (const float*)d_in[21];
  P.w_gs  = (const float*)d_in[22]; P.b_gs  = (const float*)d_in[23];
  P.w_glat= (const float*)d_in[24]; P.b_glat= (const float*)d_in[25];
  P.w_slat= (const float*)d_in[26]; P.b_slat= (const float*)d_in[27];
  P.w_d1gpi  = (const float*)d_in[28]; P.b_d1gpi  = (const float*)d_in[29];
  P.w_stngpi = (const float*)d_in[30]; P.b_stngpi = (const float*)d_in[31];
  P.w_ih = (const float*)d_in[32]; P.b_ih = (const float*)d_in[33];
  P.w_hh = (const float*)d_in[34]; P.b_hh = (const float*)d_in[35];
  P.out  = (float*)d_out;
  bg_main<<<NBLK, NTHR, 0, stream>>>(P);
}

// Round 6
// 410.495 us; speedup vs baseline: 11.9799x; 1.4609x over previous
//
#include <hip/hip_runtime.h>

// BasalGanglia fused kernel (MI355X / gfx950). R5 passed at 513us but spilled
// ~40 VGPR/thread (WRITE_SIZE 20.7MB of scratch). R6: LDS-staged small weight
// frags (kill spills), swapped MFMA operands (wide b64/b128 writes), fast
// transcendentals, 4 barriers/iter, xgpe double-buffered (fixes R5 race).

typedef _Float16 f16_t;
typedef _Float16 f16x8 __attribute__((ext_vector_type(8)));
typedef _Float16 f16x4 __attribute__((ext_vector_type(4)));
typedef float floatx4 __attribute__((ext_vector_type(4)));

#define BTOT 8192
#define BM   32
#define NTHR 512
#define NBLK 256
#define VSTR 328   // f16 stride; dword-stride 164 -> uniform 8-lane bank groups (min)
#define XST  32    // xgpe/hxf row stride (f16), k-pad zeroed

struct Params {
  const float *stimulus, *deltavf, *hx0, *cx0;
  const float *w_vf0, *b_vf0, *w_vf1, *b_vf1, *w_vf2, *b_vf2, *w_vf3, *b_vf3;
  const float *w_jd1, *b_jd1, *w_jd2, *b_jd2, *w_kd1, *b_kd1, *w_kd2, *b_kd2;
  const float *w_sg, *b_sg, *w_gs, *b_gs, *w_glat, *b_glat, *w_slat, *b_slat;
  const float *w_d1gpi, *b_d1gpi, *w_stngpi, *b_stngpi;
  const float *w_ih, *b_ih, *w_hh, *b_hh;
  float* out;
};

struct __align__(16) Smem {
  f16_t vstn[BM * VSTR];        // 20992 B
  f16_t xgpe[2][BM * XST];      // 4096 (double buffer)
  f16_t hxf[BM * XST];          // 2048
  f16_t wB2[21 * 512];          // 21504: t<19 gs-frag, t=19/20 glat-frag
  f16_t wsp[10 * 512];          // 10240: stngpi frags
  f16_t whh[5 * 512];           // 5120: w_hh gate frags
  union { float h1f[BM * 128]; float scr[3200]; float gates[BM * 80]; } u; // 16384
  float h0f[BM * 64];           // 8192
  float V_D2f[BM * 20];         // 2560
  float bsumS[304];             // b_slat+b_gs, pad->0
  float bsg[20];                // b_sg+b_glat
  float bihh[80], wih0[80], wih1[80];
  float DPs[BM * 2], vgpis[BM * 2], lamS[BM];
};

__device__ __forceinline__ float rcp_f(float x) { return __builtin_amdgcn_rcpf(x); }
__device__ __forceinline__ float sigm_fast(float x) { return rcp_f(1.f + __expf(-x)); }
__device__ __forceinline__ float tanh_fast(float x) { return 1.f - 2.f * rcp_f(1.f + __expf(2.f * x)); }

// 8 f32 weights row[k0..k0+7] -> f16x8, zero for k>=kmax or !valid (4-granular).
__device__ __forceinline__ f16x8 ldfrag(const float* row, int k0, int kmax, bool valid) {
  float4 z = make_float4(0.f, 0.f, 0.f, 0.f);
  int nv = valid ? (kmax - k0) : 0;
  float4 f0 = (nv >= 4) ? *(const float4*)(row + k0) : z;
  float4 f1 = (nv >= 8) ? *(const float4*)(row + k0 + 4) : z;
  f16x8 r;
  r[0] = (f16_t)f0.x; r[1] = (f16_t)f0.y; r[2] = (f16_t)f0.z; r[3] = (f16_t)f0.w;
  r[4] = (f16_t)f1.x; r[5] = (f16_t)f1.y; r[6] = (f16_t)f1.z; r[7] = (f16_t)f1.w;
  return r;
}

__global__ __launch_bounds__(NTHR, 2) void bg_main(Params P) {
  __shared__ Smem S;
  const int tid  = threadIdx.x;
  const int lane = tid & 63;
  const int wv   = tid >> 6;
  const int q    = lane >> 4;
  const int cl   = lane & 15;
  const int row0 = blockIdx.x * BM;
  const floatx4 zf = {0.f, 0.f, 0.f, 0.f};

  // ================= init + LDS weight-frag staging =================
  if (tid < BM) S.lamS[tid] = sigm_fast(P.deltavf[row0 + tid]);
  for (int i = tid; i < BM * 2; i += NTHR) S.vgpis[i] = 0.f;
  for (int i = tid; i < 2 * BM * XST; i += NTHR) ((f16_t*)S.xgpe)[i] = (f16_t)0.f;
  for (int i = tid; i < BM * XST; i += NTHR) {
    int m = i >> 5, j = i & 31;
    S.hxf[i] = (j < 20) ? (f16_t)P.hx0[row0 * 20 + m * 20 + j] : (f16_t)0.f;
  }
  for (int i = tid; i < BM * VSTR; i += NTHR) S.vstn[i] = (f16_t)0.f;
  for (int i = tid; i < 21 * 512; i += NTHR) {        // gs / glat frags
    int t = i >> 9, l = (i >> 3) & 63, jj = i & 7;
    int c2 = l & 15, k = ((l >> 4) << 3) + jj;
    float v = 0.f;
    if (t < 19) { int n = t * 16 + c2; if (n < 300 && k < 20) v = P.w_gs[n * 20 + k]; }
    else        { int g = (t - 19) * 16 + c2; if (g < 20 && k < 20) v = P.w_glat[g * 20 + k]; }
    S.wB2[i] = (f16_t)v;
  }
  for (int i = tid; i < 10 * 512; i += NTHR) {        // stngpi frags
    int c = i >> 9, l = (i >> 3) & 63, jj = i & 7;
    int p = l & 15, k = c * 32 + ((l >> 4) << 3) + jj;
    float v = (p < 2 && k < 300) ? P.w_stngpi[p * 300 + k] : 0.f;
    S.wsp[i] = (f16_t)v;
  }
  for (int i = tid; i < 5 * 512; i += NTHR) {         // w_hh gate frags
    int t = i >> 9, l = (i >> 3) & 63, jj = i & 7;
    int g = t * 16 + (l & 15), k = ((l >> 4) << 3) + jj;
    S.whh[i] = (f16_t)((k < 20) ? P.w_hh[g * 20 + k] : 0.f);
  }
  for (int i = tid; i < 304; i += NTHR) S.bsumS[i] = (i < 300) ? (P.b_slat[i] + P.b_gs[i]) : 0.f;
  for (int i = tid; i < 20; i += NTHR)  S.bsg[i] = P.b_sg[i] + P.b_glat[i];
  for (int i = tid; i < 80; i += NTHR) {
    S.bihh[i] = P.b_ih[i] + P.b_hh[i];
    S.wih0[i] = P.w_ih[i * 2 + 0];
    S.wih1[i] = P.w_ih[i * 2 + 1];
  }

  { // h0 = relu(stim @ w_vf0^T + b)
    int o = tid & 63, mb = (tid >> 6) * 4;
    const float4* wr = (const float4*)(P.w_vf0 + o * 300);
    float bias = P.b_vf0[o], a[4];
#pragma unroll
    for (int u = 0; u < 4; ++u) a[u] = bias;
    for (int kq = 0; kq < 75; ++kq) {
      float4 w = wr[kq];
#pragma unroll
      for (int u = 0; u < 4; ++u) {
        float4 v = *(const float4*)(P.stimulus + (size_t)(row0 + mb + u) * 300 + kq * 4);
        a[u] = fmaf(v.x, w.x, a[u]); a[u] = fmaf(v.y, w.y, a[u]);
        a[u] = fmaf(v.z, w.z, a[u]); a[u] = fmaf(v.w, w.w, a[u]);
      }
    }
#pragma unroll
    for (int u = 0; u < 4; ++u) S.h0f[(mb + u) * 64 + o] = fmaxf(a[u], 0.f);
  }
  __syncthreads();
  { // h1
    int o = tid & 127, mb = (tid >> 7) * 8;
    const float* wr = P.w_vf1 + o * 64;
    float bias = P.b_vf1[o], a[8];
#pragma unroll
    for (int u = 0; u < 8; ++u) a[u] = bias;
    for (int k = 0; k < 64; ++k) {
      float w = wr[k];
#pragma unroll
      for (int u = 0; u < 8; ++u) a[u] = fmaf(S.h0f[(mb + u) * 64 + k], w, a[u]);
    }
#pragma unroll
    for (int u = 0; u < 8; ++u) S.u.h1f[(mb + u) * 128 + o] = fmaxf(a[u], 0.f);
  }
  __syncthreads();
  { // h2 -> h0f
    int o = tid & 63, mb = (tid >> 6) * 4;
    const float* wr = P.w_vf2 + o * 128;
    float bias = P.b_vf2[o], a[4];
#pragma unroll
    for (int u = 0; u < 4; ++u) a[u] = bias;
    for (int k = 0; k < 128; ++k) {
      float w = wr[k];
#pragma unroll
      for (int u = 0; u < 4; ++u) a[u] = fmaf(S.u.h1f[(mb + u) * 128 + k], w, a[u]);
    }
#pragma unroll
    for (int u = 0; u < 4; ++u) S.h0f[(mb + u) * 64 + o] = fmaxf(a[u], 0.f);
  }
  __syncthreads();
  { // drives -> scr[0:2560); vt output
    int oid = tid & 127, mb = (tid >> 7) * 8;
    if (oid < 80) {
      int which = oid / 20, o = oid - which * 20;
      const float *wp, *bp;
      if (which == 0)      { wp = P.w_jd1; bp = P.b_jd1; }
      else if (which == 1) { wp = P.w_jd2; bp = P.b_jd2; }
      else if (which == 2) { wp = P.w_kd1; bp = P.b_kd1; }
      else                 { wp = P.w_kd2; bp = P.b_kd2; }
      float bias = bp[o], a[8];
#pragma unroll
      for (int u = 0; u < 8; ++u) a[u] = bias;
      for (int kq = 0; kq < 75; ++kq) {
        float4 w = *(const float4*)(wp + o * 300 + kq * 4);
#pragma unroll
        for (int u = 0; u < 8; ++u) {
          float4 v = *(const float4*)(P.stimulus + (size_t)(row0 + mb + u) * 300 + kq * 4);
          a[u] = fmaf(v.x, w.x, a[u]); a[u] = fmaf(v.y, w.y, a[u]);
          a[u] = fmaf(v.z, w.z, a[u]); a[u] = fmaf(v.w, w.w, a[u]);
        }
      }
#pragma unroll
      for (int u = 0; u < 8; ++u) S.u.scr[which * 640 + (mb + u) * 20 + o] = a[u];
    }
    if (tid < BM) {
      float a = P.b_vf3[0];
      for (int k = 0; k < 64; ++k) a = fmaf(S.h0f[tid * 64 + k], P.w_vf3[k], a);
      P.out[(size_t)BTOT * 20 + row0 + tid] = tanh_fast(a);
    }
  }
  __syncthreads();
  for (int i = tid; i < BM * 20; i += NTHR) { // FF -> V_D1 scr[2560:), V_D2f
    int m = i / 20;
    float j1 = S.u.scr[i],        j2 = S.u.scr[640 + i];
    float k1 = S.u.scr[1280 + i], k2 = S.u.scr[1920 + i];
    float L = S.lamS[m], v1 = 0.f, v2 = 0.f;
    for (int s = 0; s < 20; ++s) {
      v1 = sigm_fast(L * (j1 * (1.f - v1) + (1.f - k1) * v1));
      v2 = sigm_fast(L * (j2 * (1.f - v2) + (1.f - k2) * v2));
    }
    S.u.scr[2560 + i] = v1;
    S.V_D2f[i] = v2;
  }
  __syncthreads();
  if (tid < BM * 2) { // V_GPi_DP
    int m = tid >> 1, p2 = tid & 1;
    float a = P.b_d1gpi[p2];
    for (int o = 0; o < 20; ++o) a = fmaf(S.u.scr[2560 + m * 20 + o], P.w_d1gpi[p2 * 20 + o], a);
    S.DPs[tid] = a;
  }
  __syncthreads();

  // ================= register-resident slat/sg A-frags =================
  // A-frag (16x16x32): lane holds A[row=lane&15][k=q*8+j].
  f16x8 Ws[3][10];
#pragma unroll
  for (int j = 0; j < 3; ++j) {
    int t = wv + 8 * j;
    if (t < 19) {
      int n = t * 16 + cl;
#pragma unroll
      for (int c = 0; c < 10; ++c)
        Ws[j][c] = ldfrag(P.w_slat + (size_t)(n < 300 ? n : 0) * 300, c * 32 + q * 8, 300, n < 300);
    } else if (t < 21) {
      int g = (t - 19) * 16 + cl;
#pragma unroll
      for (int c = 0; c < 10; ++c)
        Ws[j][c] = ldfrag(P.w_sg + (size_t)(g < 20 ? g : 0) * 300, c * 32 + q * 8, 300, g < 20);
    } else {
      f16x8 z;
#pragma unroll
      for (int e = 0; e < 8; ++e) z[e] = (f16_t)0.f;
#pragma unroll
      for (int c = 0; c < 10; ++c) Ws[j][c] = z;
    }
  }
  const float lam0 = S.lamS[cl], lam1 = S.lamS[cl + 16];
  const float bstn0 = P.b_stngpi[0], bstn1 = P.b_stngpi[1];
  // LSTM thread-owned state: e0 = tid (always valid, 640 elems), e1 = tid+512
  const int e0 = tid,        m0 = e0 / 20, j0 = e0 - m0 * 20;
  const int e1 = tid + NTHR, m1 = e1 / 20, j1 = e1 - m1 * 20;
  const bool hase1 = (tid < BM * 20 - NTHR);
  float cxr0 = P.cx0[row0 * 20 + e0], hxr0 = P.hx0[row0 * 20 + e0];
  float cxr1 = hase1 ? P.cx0[row0 * 20 + e1] : 0.f;
  float hxr1 = hase1 ? P.hx0[row0 * 20 + e1] : 0.f;

  float xs[3][2][4];
#pragma unroll
  for (int j = 0; j < 3; ++j)
#pragma unroll
    for (int mf = 0; mf < 2; ++mf)
#pragma unroll
      for (int r = 0; r < 4; ++r) xs[j][mf][r] = 0.f;

  // ================= STN recurrence, 50 iterations =================
  for (int it = 0; it < 50; ++it) {
    const int po = it & 1, pn = po ^ 1;
    floatx4 acc[3][2];
#pragma unroll
    for (int j = 0; j < 3; ++j) { acc[j][0] = zf; acc[j][1] = zf; }

    // ---- Phase A: D[n][batch] = [slat|sg] @ vstn^T (+ glat @ xgpe_old^T) ----
#pragma unroll
    for (int c = 0; c < 10; ++c) {
      f16x8 b0 = *(const f16x8*)&S.vstn[cl * VSTR + c * 32 + q * 8];
      f16x8 b1 = *(const f16x8*)&S.vstn[(16 + cl) * VSTR + c * 32 + q * 8];
#pragma unroll
      for (int j = 0; j < 3; ++j) {
        if (wv + 8 * j < 21) {
          acc[j][0] = __builtin_amdgcn_mfma_f32_16x16x32_f16(Ws[j][c], b0, acc[j][0], 0, 0, 0);
          acc[j][1] = __builtin_amdgcn_mfma_f32_16x16x32_f16(Ws[j][c], b1, acc[j][1], 0, 0, 0);
        }
      }
    }
    if (wv == 3 || wv == 4) {
      f16x8 Wg = *(const f16x8*)&S.wB2[(wv + 16) * 512 + lane * 8];
      f16x8 g0 = *(const f16x8*)&S.xgpe[po][cl * XST + q * 8];
      f16x8 g1 = *(const f16x8*)&S.xgpe[po][(16 + cl) * XST + q * 8];
      acc[2][0] = __builtin_amdgcn_mfma_f32_16x16x32_f16(Wg, g0, acc[2][0], 0, 0, 0);
      acc[2][1] = __builtin_amdgcn_mfma_f32_16x16x32_f16(Wg, g1, acc[2][1], 0, 0, 0);
      int g0i = (wv - 3) * 16 + q * 4;
      if (g0i < 20) {
        floatx4 bg4 = *(const floatx4*)&S.bsg[g0i];
#pragma unroll
        for (int mf = 0; mf < 2; ++mf) {
          int batch = cl + 16 * mf;
          floatx4 vd4 = *(const floatx4*)&S.V_D2f[batch * 20 + g0i];
          f16x4 pk;
#pragma unroll
          for (int r = 0; r < 4; ++r) pk[r] = (f16_t)(acc[2][mf][r] + bg4[r] - vd4[r]);
          *(f16x4*)&S.xgpe[pn][batch * XST + g0i] = pk;
        }
      }
    }
    __syncthreads(); // b1: xgpe_new ready

    // ---- Phase B: acc += gs @ xgpe_new^T; xstn update; vstn_new (b64) ----
    {
      f16x8 x0 = *(const f16x8*)&S.xgpe[pn][cl * XST + q * 8];
      f16x8 x1 = *(const f16x8*)&S.xgpe[pn][(16 + cl) * XST + q * 8];
#pragma unroll
      for (int j = 0; j < 3; ++j) {
        int t = wv + 8 * j;
        if (t < 19) {
          f16x8 Wg = *(const f16x8*)&S.wB2[t * 512 + lane * 8];
          acc[j][0] = __builtin_amdgcn_mfma_f32_16x16x32_f16(Wg, x0, acc[j][0], 0, 0, 0);
          acc[j][1] = __builtin_amdgcn_mfma_f32_16x16x32_f16(Wg, x1, acc[j][1], 0, 0, 0);
        }
      }
#pragma unroll
      for (int j = 0; j < 3; ++j) {
        int t = wv + 8 * j;
        if (t < 19) {
          int n0 = t * 16 + q * 4;
          if (!(t == 18 && q == 3)) {  // n0..n0+3 all < 300
            floatx4 bs4 = *(const floatx4*)&S.bsumS[n0];
#pragma unroll
            for (int mf = 0; mf < 2; ++mf) {
              float lm = mf ? lam1 : lam0;
              f16x4 pk;
#pragma unroll
              for (int r = 0; r < 4; ++r) {
                float xo = xs[j][mf][r];
                float xn = xo + (1.0f / 3.0f) * (acc[j][mf][r] + bs4[r] - xo);
                xs[j][mf][r] = xn;
                pk[r] = (f16_t)tanh_fast(lm * xn);
              }
              *(f16x4*)&S.vstn[(cl + 16 * mf) * VSTR + n0] = pk;
            }
          }
        }
      }
    }
    __syncthreads(); // b2: vstn_new ready

    // ---- Phase C: wave5 stngpi->vgpi; waves0-4 w_hh@hx gates ----
    if (wv == 5) {
      floatx4 ip0 = zf, ip1 = zf;
#pragma unroll
      for (int c = 0; c < 10; ++c) {
        f16x8 Wp = *(const f16x8*)&S.wsp[c * 512 + lane * 8];
        f16x8 b0 = *(const f16x8*)&S.vstn[cl * VSTR + c * 32 + q * 8];
        f16x8 b1 = *(const f16x8*)&S.vstn[(16 + cl) * VSTR + c * 32 + q * 8];
        ip0 = __builtin_amdgcn_mfma_f32_16x16x32_f16(Wp, b0, ip0, 0, 0, 0);
        ip1 = __builtin_amdgcn_mfma_f32_16x16x32_f16(Wp, b1, ip1, 0, 0, 0);
      }
      if (q == 0) {
#pragma unroll
        for (int mf = 0; mf < 2; ++mf) {
          int batch = cl + 16 * mf;
          float lm = mf ? lam1 : lam0;
#pragma unroll
          for (int p = 0; p < 2; ++p) {
            float raw = (mf ? ip1[p] : ip0[p]) + (p ? bstn1 : bstn0);
            float ipv = lm * raw;
            int idx = batch * 2 + p;
            float v = S.vgpis[idx];
            v = v + 0.1f * (-v - S.DPs[idx] + 2.f * ipv);
            S.vgpis[idx] = v;
          }
        }
      }
    } else if (wv < 5) {
      f16x8 Wh = *(const f16x8*)&S.whh[wv * 512 + lane * 8];
      f16x8 h0 = *(const f16x8*)&S.hxf[cl * XST + q * 8];
      f16x8 h1 = *(const f16x8*)&S.hxf[(16 + cl) * XST + q * 8];
      floatx4 gA = __builtin_amdgcn_mfma_f32_16x16x32_f16(Wh, h0, zf, 0, 0, 0);
      floatx4 gB = __builtin_amdgcn_mfma_f32_16x16x32_f16(Wh, h1, zf, 0, 0, 0);
      int gb = wv * 16 + q * 4;
      *(floatx4*)&S.u.gates[cl * 80 + gb] = gA;
      *(floatx4*)&S.u.gates[(cl + 16) * 80 + gb] = gB;
    }
    __syncthreads(); // b3: vgpis + hh-gates ready

    // ---- LSTM pointwise (rank-2 w_ih term folded in) ----
    {
      float v0 = S.vgpis[m0 * 2], v1 = S.vgpis[m0 * 2 + 1];
      float gi = S.u.gates[m0 * 80 + j0]      + S.bihh[j0]      - S.wih0[j0] * v0      - S.wih1[j0] * v1;
      float gf = S.u.gates[m0 * 80 + 20 + j0] + S.bihh[20 + j0] - S.wih0[20 + j0] * v0 - S.wih1[20 + j0] * v1;
      float gg = S.u.gates[m0 * 80 + 40 + j0] + S.bihh[40 + j0] - S.wih0[40 + j0] * v0 - S.wih1[40 + j0] * v1;
      float go = S.u.gates[m0 * 80 + 60 + j0] + S.bihh[60 + j0] - S.wih0[60 + j0] * v0 - S.wih1[60 + j0] * v1;
      float cn = sigm_fast(gf) * cxr0 + sigm_fast(gi) * tanh_fast(gg);
      cxr0 = cn;
      hxr0 = sigm_fast(go) * tanh_fast(cn);
      S.hxf[m0 * XST + j0] = (f16_t)hxr0;
    }
    if (hase1) {
      float v0 = S.vgpis[m1 * 2], v1 = S.vgpis[m1 * 2 + 1];
      float gi = S.u.gates[m1 * 80 + j1]      + S.bihh[j1]      - S.wih0[j1] * v0      - S.wih1[j1] * v1;
      float gf = S.u.gates[m1 * 80 + 20 + j1] + S.bihh[20 + j1] - S.wih0[20 + j1] * v0 - S.wih1[20 + j1] * v1;
      float gg = S.u.gates[m1 * 80 + 40 + j1] + S.bihh[40 + j1] - S.wih0[40 + j1] * v0 - S.wih1[40 + j1] * v1;
      float go = S.u.gates[m1 * 80 + 60 + j1] + S.bihh[60 + j1] - S.wih0[60 + j1] * v0 - S.wih1[60 + j1] * v1;
      float cn = sigm_fast(gf) * cxr1 + sigm_fast(gi) * tanh_fast(gg);
      cxr1 = cn;
      hxr1 = sigm_fast(go) * tanh_fast(cn);
      S.hxf[m1 * XST + j1] = (f16_t)hxr1;
    }
    __syncthreads(); // b4: hxf ready for next Phase C
  }

  // ---- output hx from registers ----
  P.out[(size_t)row0 * 20 + e0] = hxr0;
  if (hase1) P.out[(size_t)row0 * 20 + e1] = hxr1;
}

extern "C" void kernel_launch(void* const* d_in, const int* in_sizes, int n_in,
                              void* d_out, int out_size, void* d_ws, size_t ws_size,
                              hipStream_t stream) {
  (void)in_sizes; (void)n_in; (void)out_size; (void)d_ws; (void)ws_size;
  Params P;
  P.stimulus = (const float*)d_in[0];
  P.deltavf  = (const float*)d_in[1];
  P.hx0 = (const float*)d_in[2];
  P.cx0 = (const float*)d_in[3];
  P.w_vf0 = (const float*)d_in[4];  P.b_vf0 = (const float*)d_in[5];
  P.w_vf1 = (const float*)d_in[6];  P.b_vf1 = (const float*)d_in[7];
  P.w_vf2 = (const float*)d_in[8];  P.b_vf2 = (const float*)d_in[9];
  P.w_vf3 = (const float*)d_in[10]; P.b_vf3 = (const float*)d_in[11];
  P.w_jd1 = (const float*)d_in[12]; P.b_jd1 = (const float*)d_in[13];
  P.w_jd2 = (const float*)d_in[14]; P.b_jd2 = (const float*)d_in[15];
  P.w_kd1 = (const float*)d_in[16]; P.b_kd1 = (const float*)d_in[17];
  P.w_kd2 = (const float*)d_in[18]; P.b_kd2 = (const float*)d_in[19];
  P.w_sg  = (const float*)d_in[20]; P.b_sg  = (const float*)d_in[21];
  P.w_gs  = (const float*)d_in[22]; P.b_gs  = (const float*)d_in[23];
  P.w_glat= (const float*)d_in[24]; P.b_glat= (const float*)d_in[25];
  P.w_slat= (const float*)d_in[26]; P.b_slat= (const float*)d_in[27];
  P.w_d1gpi  = (const float*)d_in[28]; P.b_d1gpi  = (const float*)d_in[29];
  P.w_stngpi = (const float*)d_in[30]; P.b_stngpi = (const float*)d_in[31];
  P.w_ih = (const float*)d_in[32]; P.b_ih = (const float*)d_in[33];
  P.w_hh = (const float*)d_in[34]; P.b_hh = (const float*)d_in[35];
  P.out  = (float*)d_out;
  bg_main<<<NBLK, NTHR, 0, stream>>>(P);
}